// Round 10
// baseline (153.496 us; speedup 1.0000x reference)
//
#include <hip/hip_runtime.h>
#include <hip/hip_bf16.h>

// B=4, S=256, H=768, P=54.
// out[b,i,j,p] = valid ? relu(ha[b,i]+hb[b,j]+bp1) . Wp2[p] + bp2[p] : 0
// valid = cand[i] & cand[j] & i!=j; cand = (relu(x W1^T + b1) . W2[0] + b2[0]) > 0.5
// cand rate ~1% -> sparse pairs.
// R3: 139.8. R6: coop fusion disaster; harness overhead calibrated ~96us/iter.
// R7: 137.5 BEST (f32 split-K gemm + hpart + span_cand). R8: fused-zero regression.
// R9: KSPLIT=8 neutral -> gemm not occupancy-bound; f32 path at local optimum.
// R10: replace f32 gemm+hpart+span_cand with bf16 hi/lo-split MFMA GEMM:
//      S = (xh+xl)(wh+wl)^T via 3 chained mfma_f32_16x16x32_bf16; full-K per
//      block; fused relu.w2 epilogue + atomicAdd span (no hpart, no LDS).
//      A/B frags are 16B K-contiguous runs (A[m=lane&15][k=quad*8+j],
//      B[k=quad*8+j][n=lane&15], C/D col=lane&15 row=quad*4+reg — m89/m120).
//      Error ~1e-4 worst-case on span only; pair logits stay f32.

#define M_ROWS 1024
#define HDIM 768
#define PDIM 54
#define MAXC 256
#define KCHUNK 16
#define NKC (HDIM / KCHUNK) // 48

// ---- workspace layout (bytes) ----
#define CNT_OFF      0           // 2 ints: candCnt, pairCnt
#define SPAN_OFF     4096        // 1024 f32
#define CANDIDX_OFF  8192        // MAXC int
#define CANDSLOT_OFF 12288       // 1024 int
#define PAIR_OFF     16384       // up to 261120 int
#define XH_OFF       1064960     // 1024*768 bf16 = 1572864 B
#define XL_OFF       2637824
#define WH_OFF       4210688     // 768*768 bf16 = 1179648 B
#define WL_OFF       5390336
#define HA_OFF       6569984     // MAXC*768 f32
#define HB_OFF       7356416

typedef short bf16x8 __attribute__((ext_vector_type(8)));
typedef float f32x4  __attribute__((ext_vector_type(4)));

__device__ __forceinline__ unsigned short f2bf(float f) {
    unsigned u = __float_as_uint(f);
    return (unsigned short)((u + 0x7FFFu + ((u >> 16) & 1u)) >> 16);
}
__device__ __forceinline__ float bf2f(unsigned short h) {
    return __uint_as_float((unsigned)h << 16);
}

// ============ convert: x,W1 -> hi/lo bf16; zero span+counters ============
// grid 1344*256 = 344064 threads = (786432 + 589824)/4 float4-quads.
__global__ __launch_bounds__(256) void convert_kernel(
    const float* __restrict__ x, const float* __restrict__ W1,
    unsigned short* __restrict__ xh, unsigned short* __restrict__ xl,
    unsigned short* __restrict__ wh, unsigned short* __restrict__ wl,
    float* __restrict__ span, int* __restrict__ counters)
{
    int tid = blockIdx.x * 256 + threadIdx.x;
    if (tid < 1024) span[tid] = 0.f;
    if (tid < 2) counters[tid] = 0;

    const int NX = (M_ROWS * HDIM) / 4;   // 196608
    float4 v;
    unsigned short* dh; unsigned short* dl; int q;
    if (tid < NX) {
        v = ((const float4*)x)[tid];
        dh = xh; dl = xl; q = tid;
    } else {
        q = tid - NX;                     // < 147456
        v = ((const float4*)W1)[q];
        dh = wh; dl = wl;
    }
    ushort4 h, l;
    h.x = f2bf(v.x); l.x = f2bf(v.x - bf2f(h.x));
    h.y = f2bf(v.y); l.y = f2bf(v.y - bf2f(h.y));
    h.z = f2bf(v.z); l.z = f2bf(v.z - bf2f(h.z));
    h.w = f2bf(v.w); l.w = f2bf(v.w - bf2f(h.w));
    ((ushort4*)dh)[q] = h;
    ((ushort4*)dl)[q] = l;
}

// ============ bf16-split MFMA GEMM + fused span epilogue ============
// grid (16,12), 256 thr = 4 waves. Wave strip: 16 m x 64 n. No LDS, no barriers.
__global__ __launch_bounds__(256) void gemm_span_mfma(
    const unsigned short* __restrict__ xh, const unsigned short* __restrict__ xl,
    const unsigned short* __restrict__ wh, const unsigned short* __restrict__ wl,
    const float* __restrict__ b1, const float* __restrict__ w2row,
    float* __restrict__ span)
{
    const int t = threadIdx.x;
    const int wave = t >> 6, lane = t & 63;
    const int quad = lane >> 4, c = lane & 15;
    const int m0 = blockIdx.x * 64 + wave * 16;
    const int n0 = blockIdx.y * 64;

    const unsigned short* xhp = xh + (size_t)(m0 + c) * HDIM + quad * 8;
    const unsigned short* xlp = xl + (size_t)(m0 + c) * HDIM + quad * 8;
    const unsigned short* whp = wh + (size_t)(n0 + c) * HDIM + quad * 8;
    const unsigned short* wlp = wl + (size_t)(n0 + c) * HDIM + quad * 8;

    f32x4 acc[4] = {};

    #pragma unroll 2
    for (int k0 = 0; k0 < HDIM; k0 += 32) {
        bf16x8 Ah = *(const bf16x8*)(xhp + k0);
        bf16x8 Al = *(const bf16x8*)(xlp + k0);
        #pragma unroll
        for (int nt = 0; nt < 4; ++nt) {
            bf16x8 Bh = *(const bf16x8*)(whp + (size_t)nt * 16 * HDIM + k0);
            bf16x8 Bl = *(const bf16x8*)(wlp + (size_t)nt * 16 * HDIM + k0);
            acc[nt] = __builtin_amdgcn_mfma_f32_16x16x32_bf16(Ah, Bh, acc[nt], 0, 0, 0);
            acc[nt] = __builtin_amdgcn_mfma_f32_16x16x32_bf16(Ah, Bl, acc[nt], 0, 0, 0);
            acc[nt] = __builtin_amdgcn_mfma_f32_16x16x32_bf16(Al, Bh, acc[nt], 0, 0, 0);
        }
    }

    // epilogue: h = relu(S + b1[n]); part[r] = sum_n h * w2[n] over wave's 64-n
    float part[4] = {0.f, 0.f, 0.f, 0.f};
    #pragma unroll
    for (int nt = 0; nt < 4; ++nt) {
        int n_abs = n0 + nt * 16 + c;
        float b1v = b1[n_abs], w2v = w2row[n_abs];
        #pragma unroll
        for (int r = 0; r < 4; ++r) {
            float h = acc[nt][r] + b1v;
            h = h > 0.f ? h : 0.f;
            part[r] += h * w2v;
        }
    }
    #pragma unroll
    for (int mask = 1; mask < 16; mask <<= 1) {
        #pragma unroll
        for (int r = 0; r < 4; ++r) part[r] += __shfl_xor(part[r], mask, 64);
    }
    if (c < 4) {
        #pragma unroll
        for (int r = 0; r < 4; ++r)
            if (c == r) atomicAdd(&span[m0 + quad * 4 + r], part[r]);
    }
}

// ============ cand compaction (R2/R3-proven) ============
__global__ void cand_kernel(const float* __restrict__ span, const float* __restrict__ b2,
                            int* __restrict__ candCount, int* __restrict__ candIdx,
                            int* __restrict__ candSlot)
{
    int i = blockIdx.x * 256 + threadIdx.x;
    float v = span[i] + b2[0];
    if (v > 0.5f) {
        int s = atomicAdd(candCount, 1);
        if (s < MAXC) { candIdx[s] = i; candSlot[i] = s; }
        else candSlot[i] = -1;
    } else {
        candSlot[i] = -1;
    }
}

// ============ hab: k-split across blocks (R7-proven, unchanged) ============
__global__ __launch_bounds__(256) void hab_kernel(
    const float* __restrict__ x, const float* __restrict__ Wp1,
    const int* __restrict__ candCount, const int* __restrict__ candIdx,
    float* __restrict__ ha, float* __restrict__ hb)
{
    __shared__ float xs[HDIM];
    __shared__ float red[2][KCHUNK][17];
    int nc = *candCount; if (nc > MAXC) nc = MAXC;
    const int nitems = nc * NKC;
    const int kk  = threadIdx.x >> 4;
    const int hb0 = (threadIdx.x & 15) * 4;

    for (int item = blockIdx.x; item < nitems; item += gridDim.x) {
        int slot = item / NKC;
        int kc   = item % NKC;
        int row  = candIdx[slot];

        for (int h = threadIdx.x; h < HDIM; h += 256)
            xs[h] = x[(size_t)row * HDIM + h];
        __syncthreads();

        int k = kc * KCHUNK + kk;
        const float* wr = Wp1 + (size_t)k * (2 * HDIM);
        float sa = 0.f, sb = 0.f;
        #pragma unroll
        for (int h = hb0; h < HDIM; h += 64) {
            float4 xv = *(const float4*)(xs + h);
            float4 wa = *(const float4*)(wr + h);
            float4 wb = *(const float4*)(wr + HDIM + h);
            sa += xv.x * wa.x + xv.y * wa.y + xv.z * wa.z + xv.w * wa.w;
            sb += xv.x * wb.x + xv.y * wb.y + xv.z * wb.z + xv.w * wb.w;
        }
        red[0][kk][threadIdx.x & 15] = sa;
        red[1][kk][threadIdx.x & 15] = sb;
        __syncthreads();

        if (threadIdx.x < 32) {
            int which = threadIdx.x >> 4;
            int kk2   = threadIdx.x & 15;
            float s = 0.f;
            #pragma unroll
            for (int g = 0; g < 16; ++g) s += red[which][kk2][g];
            float* dst = which == 0 ? ha : hb;
            dst[(size_t)slot * HDIM + kc * KCHUNK + kk2] = s;
        }
        __syncthreads();
    }
}

// ============ build valid pair list (R7-proven) ============
__global__ void pairs_kernel(const int* __restrict__ candSlot,
                             int* __restrict__ pairCount, int* __restrict__ pairList)
{
    int idx = blockIdx.x * 256 + threadIdx.x;
    int b = idx >> 16;
    int i = (idx >> 8) & 255;
    int j = idx & 255;
    if (i == j) return;
    if (candSlot[b * 256 + i] >= 0 && candSlot[b * 256 + j] >= 0) {
        int p = atomicAdd(pairCount, 1);
        pairList[p] = idx;
    }
}

// ============ sparse pair logits (R7-proven) ============
__global__ __launch_bounds__(256) void pair_kernel(
    const float* __restrict__ ha, const float* __restrict__ hb,
    const float* __restrict__ bp1, const float* __restrict__ Wp2,
    const float* __restrict__ bp2, const int* __restrict__ candSlot,
    const int* __restrict__ pairCount, const int* __restrict__ pairList,
    float* __restrict__ out)
{
    __shared__ float v[HDIM];
    __shared__ float red[4][PDIM + 2];
    const int np = *pairCount;
    const int t = threadIdx.x;
    for (int p = blockIdx.x; p < np; p += gridDim.x) {
        int idx = pairList[p];
        int b = idx >> 16;
        int i = (idx >> 8) & 255;
        int j = idx & 255;
        int si = candSlot[b * 256 + i];
        int sj = candSlot[b * 256 + j];
        if (t < 192) {
            float4 a4 = *(const float4*)(ha + (size_t)si * HDIM + t * 4);
            float4 b4 = *(const float4*)(hb + (size_t)sj * HDIM + t * 4);
            float4 c4 = *(const float4*)(bp1 + t * 4);
            float4 r;
            r.x = a4.x + b4.x + c4.x; r.x = r.x > 0.f ? r.x : 0.f;
            r.y = a4.y + b4.y + c4.y; r.y = r.y > 0.f ? r.y : 0.f;
            r.z = a4.z + b4.z + c4.z; r.z = r.z > 0.f ? r.z : 0.f;
            r.w = a4.w + b4.w + c4.w; r.w = r.w > 0.f ? r.w : 0.f;
            *(float4*)(v + t * 4) = r;
        }
        __syncthreads();
        if (t < 216) {
            int pp  = t % PDIM;
            int seg = t / PDIM;
            const float* w = Wp2 + (size_t)pp * HDIM + seg * 192;
            const float* vv = v + seg * 192;
            float s = 0.f;
            for (int h = 0; h < 192; h += 4) {
                float4 a = *(const float4*)(vv + h);
                float4 b2_ = *(const float4*)(w + h);
                s += a.x * b2_.x + a.y * b2_.y + a.z * b2_.z + a.w * b2_.w;
            }
            red[seg][pp] = s;
        }
        __syncthreads();
        if (t < PDIM)
            out[(size_t)idx * PDIM + t] = red[0][t] + red[1][t] + red[2][t] + red[3][t] + bp2[t];
        __syncthreads();
    }
}

extern "C" void kernel_launch(void* const* d_in, const int* in_sizes, int n_in,
                              void* d_out, int out_size, void* d_ws, size_t ws_size,
                              hipStream_t stream) {
    const float* x   = (const float*)d_in[0];
    const float* W1s = (const float*)d_in[1];
    const float* b1s = (const float*)d_in[2];
    const float* W2s = (const float*)d_in[3];
    const float* b2s = (const float*)d_in[4];
    const float* Wp1 = (const float*)d_in[5];
    const float* bp1 = (const float*)d_in[6];
    const float* Wp2 = (const float*)d_in[7];
    const float* bp2 = (const float*)d_in[8];

    char* ws = (char*)d_ws;
    int*   counters = (int*)(ws + CNT_OFF);       // [0]=candCnt, [1]=pairCnt
    int*   candCnt  = counters;
    int*   pairCnt  = counters + 1;
    float* span     = (float*)(ws + SPAN_OFF);
    int*   candIdx  = (int*)(ws + CANDIDX_OFF);
    int*   candSlot = (int*)(ws + CANDSLOT_OFF);
    int*   pairList = (int*)(ws + PAIR_OFF);
    unsigned short* xh = (unsigned short*)(ws + XH_OFF);
    unsigned short* xl = (unsigned short*)(ws + XL_OFF);
    unsigned short* wh = (unsigned short*)(ws + WH_OFF);
    unsigned short* wl = (unsigned short*)(ws + WL_OFF);
    float* ha       = (float*)(ws + HA_OFF);
    float* hb       = (float*)(ws + HB_OFF);
    float* out = (float*)d_out;

    // zero output (masked regions must be exactly 0)
    hipMemsetAsync(out, 0, (size_t)out_size * sizeof(float), stream);

    convert_kernel<<<1344, 256, 0, stream>>>(x, W1s, xh, xl, wh, wl, span, counters);

    dim3 gg(M_ROWS / 64, HDIM / 64);
    gemm_span_mfma<<<gg, 256, 0, stream>>>(xh, xl, wh, wl, b1s, W2s, span);

    cand_kernel<<<4, 256, 0, stream>>>(span, b2s, candCnt, candIdx, candSlot);

    hab_kernel<<<2048, 256, 0, stream>>>(x, Wp1, candCnt, candIdx, ha, hb);

    pairs_kernel<<<1024, 256, 0, stream>>>(candSlot, pairCnt, pairList);

    pair_kernel<<<512, 256, 0, stream>>>(ha, hb, bp1, Wp2, bp2,
                                         candSlot, pairCnt, pairList, out);
}

// Round 11
// 140.404 us; speedup vs baseline: 1.0932x; 1.0932x over previous
//
#include <hip/hip_runtime.h>
#include <hip/hip_bf16.h>

// B=4, S=256, H=768, P=54.
// out[b,i,j,p] = valid ? relu(ha[b,i]+hb[b,j]+bp1) . Wp2[p] + bp2[p] : 0
// valid = cand[i] & cand[j] & i!=j; cand = (relu(x W1^T + b1) . W2[0] + b2[0]) > 0.5
// cand rate ~1% -> sparse pairs.
// R1: per-CU-BW-bound hab -> k-split. R2: split-K=4 gemm (768 blk), stride-68 LDS.
// R3: 139.8. R4/R5: multi-change regressions. R6: coop fusion disaster (340us);
//     calibrated harness overhead ~96us/iter FIXED (fills+restores).
// R7: 137.5 BEST. R8 fused-zero pair +9. R9 KSPLIT=8 neutral (gemm at LDS-BW
//     roofline: 1.21 GB LDS / 69 TB/s = 17.5us). R10 MFMA+convert +16
//     (1 wave/SIMD latency-bound, 3x work from hi/lo split).
// R11: revert to R7 verbatim — proven optimum. Structure: 96us harness +
//     9us out-zero (HBM floor) + 17us gemm (LDS floor) + ~15us small kernels/gaps.

#define M_ROWS 1024
#define HDIM 768
#define PDIM 54
#define MAXC 256            // candidate slot cap (actual nc ~27)
#define KCHUNK 16
#define NKC (HDIM / KCHUNK) // 48
#define KSPLIT 4
#define KSEG (HDIM / KSPLIT) // 192

// ---- workspace layout (bytes) ----
#define CANDCNT_OFF  0
#define PAIRCNT_OFF  4
#define CANDIDX_OFF  8192        // MAXC int
#define CANDSLOT_OFF 12288       // 1024 int (fully written each call)
#define PAIR_OFF     16384       // up to 261120 int
#define HPART_OFF    1064960     // KSPLIT*1024*768 f32 = 12 MB

// ================= split-K GEMM =================
// 64x64 tile, K-seg 192, 256 thr, 4x4 micro. hpart[z][m][n] = partial x.W1^T.
// Block (0,0,0) threads 0/1 zero candCnt/pairCnt (ws is 0xAA-poisoned).
__global__ __launch_bounds__(256) void gemm_k_kernel(
    const float* __restrict__ x, const float* __restrict__ W1,
    float* __restrict__ hpart, int* __restrict__ counters)
{
    __shared__ float As[16][68];
    __shared__ float Bs[16][68];

    if (blockIdx.x == 0 && blockIdx.y == 0 && blockIdx.z == 0 && threadIdx.x < 2)
        counters[threadIdx.x] = 0;

    const int m0 = blockIdx.x * 64;
    const int n0 = blockIdx.y * 64;
    const int kb = blockIdx.z * KSEG;
    const int t  = threadIdx.x;
    const int tm = t & 15;
    const int tn = t >> 4;
    const int r  = t >> 2;        // 0..63
    const int c4 = (t & 3) * 4;   // 0,4,8,12

    float acc[4][4] = {};

    for (int k0 = kb; k0 < kb + KSEG; k0 += 16) {
        float4 av = *(const float4*)(x  + (size_t)(m0 + r) * HDIM + k0 + c4);
        float4 bv = *(const float4*)(W1 + (size_t)(n0 + r) * HDIM + k0 + c4);
        As[c4+0][r] = av.x; As[c4+1][r] = av.y; As[c4+2][r] = av.z; As[c4+3][r] = av.w;
        Bs[c4+0][r] = bv.x; Bs[c4+1][r] = bv.y; Bs[c4+2][r] = bv.z; Bs[c4+3][r] = bv.w;
        __syncthreads();
        #pragma unroll
        for (int kk = 0; kk < 16; ++kk) {
            float a[4], b[4];
            #pragma unroll
            for (int i = 0; i < 4; ++i) a[i] = As[kk][tm * 4 + i];
            #pragma unroll
            for (int j = 0; j < 4; ++j) b[j] = Bs[kk][tn * 4 + j];
            #pragma unroll
            for (int i = 0; i < 4; ++i)
                #pragma unroll
                for (int j = 0; j < 4; ++j)
                    acc[i][j] += a[i] * b[j];
        }
        __syncthreads();
    }

    // direct float4 stores: per instr, 16 rows x 64B full lines (coalesced)
    float* dst = hpart + (size_t)blockIdx.z * (M_ROWS * HDIM);
    #pragma unroll
    for (int i = 0; i < 4; ++i) {
        float4 v = make_float4(acc[i][0], acc[i][1], acc[i][2], acc[i][3]);
        *(float4*)(dst + (size_t)(m0 + tm * 4 + i) * HDIM + n0 + tn * 4) = v;
    }
}

// reduce KSPLIT partials, relu.w2, decide cand. One block per row m.
__global__ __launch_bounds__(256) void span_cand_kernel(
    const float* __restrict__ hpart, const float* __restrict__ b1,
    const float* __restrict__ w2row, const float* __restrict__ b2,
    int* __restrict__ candCount, int* __restrict__ candIdx,
    int* __restrict__ candSlot)
{
    const int m = blockIdx.x;
    const int t = threadIdx.x;
    float p = 0.f;
    for (int n = t; n < HDIM; n += 256) {
        float v = hpart[(size_t)m * HDIM + n]
                + hpart[(size_t)(M_ROWS * HDIM) + (size_t)m * HDIM + n]
                + hpart[(size_t)(2 * M_ROWS * HDIM) + (size_t)m * HDIM + n]
                + hpart[(size_t)(3 * M_ROWS * HDIM) + (size_t)m * HDIM + n];
        v += b1[n];
        v = v > 0.f ? v : 0.f;
        p += v * w2row[n];
    }
    __shared__ float wred[4];
    #pragma unroll
    for (int off = 32; off > 0; off >>= 1) p += __shfl_down(p, off, 64);
    if ((t & 63) == 0) wred[t >> 6] = p;
    __syncthreads();
    if (t == 0) {
        float s = wred[0] + wred[1] + wred[2] + wred[3] + b2[0];
        if (s > 0.5f) {
            int sl = atomicAdd(candCount, 1);
            if (sl < MAXC) { candIdx[sl] = m; candSlot[m] = sl; }
            else candSlot[m] = -1;
        } else {
            candSlot[m] = -1;
        }
    }
}

// ================= hab: k-split across blocks =================
// work item = (slot, kc): block computes ha/hb[slot][kc*16 .. kc*16+15].
__global__ __launch_bounds__(256) void hab_kernel(
    const float* __restrict__ x, const float* __restrict__ Wp1,
    const int* __restrict__ candCount, const int* __restrict__ candIdx,
    float* __restrict__ ha, float* __restrict__ hb)
{
    __shared__ float xs[HDIM];
    __shared__ float red[2][KCHUNK][17];
    int nc = *candCount; if (nc > MAXC) nc = MAXC;
    const int nitems = nc * NKC;
    const int kk  = threadIdx.x >> 4;
    const int hb0 = (threadIdx.x & 15) * 4;

    for (int item = blockIdx.x; item < nitems; item += gridDim.x) {
        int slot = item / NKC;
        int kc   = item % NKC;
        int row  = candIdx[slot];

        for (int h = threadIdx.x; h < HDIM; h += 256)
            xs[h] = x[(size_t)row * HDIM + h];
        __syncthreads();

        int k = kc * KCHUNK + kk;
        const float* wr = Wp1 + (size_t)k * (2 * HDIM);
        float sa = 0.f, sb = 0.f;
        #pragma unroll
        for (int h = hb0; h < HDIM; h += 64) {
            float4 xv = *(const float4*)(xs + h);
            float4 wa = *(const float4*)(wr + h);
            float4 wb = *(const float4*)(wr + HDIM + h);
            sa += xv.x * wa.x + xv.y * wa.y + xv.z * wa.z + xv.w * wa.w;
            sb += xv.x * wb.x + xv.y * wb.y + xv.z * wb.z + xv.w * wb.w;
        }
        red[0][kk][threadIdx.x & 15] = sa;
        red[1][kk][threadIdx.x & 15] = sb;
        __syncthreads();

        if (threadIdx.x < 32) {
            int which = threadIdx.x >> 4;
            int kk2   = threadIdx.x & 15;
            float s = 0.f;
            #pragma unroll
            for (int g = 0; g < 16; ++g) s += red[which][kk2][g];
            float* dst = which == 0 ? ha : hb;
            dst[(size_t)slot * HDIM + kc * KCHUNK + kk2] = s;
        }
        __syncthreads();
    }
}

// ================= build valid pair list =================
__global__ void pairs_kernel(const int* __restrict__ candSlot,
                             int* __restrict__ pairCount, int* __restrict__ pairList)
{
    int idx = blockIdx.x * 256 + threadIdx.x;
    int b = idx >> 16;
    int i = (idx >> 8) & 255;
    int j = idx & 255;
    if (i == j) return;
    if (candSlot[b * 256 + i] >= 0 && candSlot[b * 256 + j] >= 0) {
        int p = atomicAdd(pairCount, 1);
        pairList[p] = idx;
    }
}

// ================= sparse pair logits =================
__global__ __launch_bounds__(256) void pair_kernel(
    const float* __restrict__ ha, const float* __restrict__ hb,
    const float* __restrict__ bp1, const float* __restrict__ Wp2,
    const float* __restrict__ bp2, const int* __restrict__ candSlot,
    const int* __restrict__ pairCount, const int* __restrict__ pairList,
    float* __restrict__ out)
{
    __shared__ float v[HDIM];
    __shared__ float red[4][PDIM + 2];
    const int np = *pairCount;
    const int t = threadIdx.x;
    for (int p = blockIdx.x; p < np; p += gridDim.x) {
        int idx = pairList[p];
        int b = idx >> 16;
        int i = (idx >> 8) & 255;
        int j = idx & 255;
        int si = candSlot[b * 256 + i];
        int sj = candSlot[b * 256 + j];
        if (t < 192) {
            float4 a4 = *(const float4*)(ha + (size_t)si * HDIM + t * 4);
            float4 b4 = *(const float4*)(hb + (size_t)sj * HDIM + t * 4);
            float4 c4 = *(const float4*)(bp1 + t * 4);
            float4 r;
            r.x = a4.x + b4.x + c4.x; r.x = r.x > 0.f ? r.x : 0.f;
            r.y = a4.y + b4.y + c4.y; r.y = r.y > 0.f ? r.y : 0.f;
            r.z = a4.z + b4.z + c4.z; r.z = r.z > 0.f ? r.z : 0.f;
            r.w = a4.w + b4.w + c4.w; r.w = r.w > 0.f ? r.w : 0.f;
            *(float4*)(v + t * 4) = r;
        }
        __syncthreads();
        if (t < 216) {
            int pp  = t % PDIM;
            int seg = t / PDIM;               // 0..3, h-range 192 each
            const float* w = Wp2 + (size_t)pp * HDIM + seg * 192;
            const float* vv = v + seg * 192;
            float s = 0.f;
            for (int h = 0; h < 192; h += 4) {
                float4 a = *(const float4*)(vv + h);
                float4 b2_ = *(const float4*)(w + h);
                s += a.x * b2_.x + a.y * b2_.y + a.z * b2_.z + a.w * b2_.w;
            }
            red[seg][pp] = s;
        }
        __syncthreads();
        if (t < PDIM)
            out[(size_t)idx * PDIM + t] = red[0][t] + red[1][t] + red[2][t] + red[3][t] + bp2[t];
        __syncthreads();
    }
}

extern "C" void kernel_launch(void* const* d_in, const int* in_sizes, int n_in,
                              void* d_out, int out_size, void* d_ws, size_t ws_size,
                              hipStream_t stream) {
    const float* x   = (const float*)d_in[0];
    const float* W1s = (const float*)d_in[1];
    const float* b1s = (const float*)d_in[2];
    const float* W2s = (const float*)d_in[3];
    const float* b2s = (const float*)d_in[4];
    const float* Wp1 = (const float*)d_in[5];
    const float* bp1 = (const float*)d_in[6];
    const float* Wp2 = (const float*)d_in[7];
    const float* bp2 = (const float*)d_in[8];

    char* ws = (char*)d_ws;
    int*   counters = (int*)(ws + CANDCNT_OFF);   // [0]=candCnt, [1]=pairCnt
    int*   candCnt  = counters;
    int*   pairCnt  = counters + 1;
    int*   candIdx  = (int*)(ws + CANDIDX_OFF);
    int*   candSlot = (int*)(ws + CANDSLOT_OFF);
    int*   pairList = (int*)(ws + PAIR_OFF);
    float* hpart    = (float*)(ws + HPART_OFF);
    float* ha       = hpart + (size_t)KSPLIT * M_ROWS * HDIM;
    float* hb       = ha + (size_t)MAXC * HDIM;
    float* out = (float*)d_out;

    // zero output (masked regions must be exactly 0)
    hipMemsetAsync(out, 0, (size_t)out_size * sizeof(float), stream);

    dim3 g(M_ROWS / 64, HDIM / 64, KSPLIT);
    gemm_k_kernel<<<g, 256, 0, stream>>>(x, W1s, hpart, counters);

    span_cand_kernel<<<M_ROWS, 256, 0, stream>>>(hpart, b1s, W2s, b2s,
                                                 candCnt, candIdx, candSlot);

    hab_kernel<<<2048, 256, 0, stream>>>(x, Wp1, candCnt, candIdx, ha, hb);

    pairs_kernel<<<1024, 256, 0, stream>>>(candSlot, pairCnt, pairList);

    pair_kernel<<<512, 256, 0, stream>>>(ha, hb, bp1, Wp2, bp2,
                                         candSlot, pairCnt, pairList, out);
}